// Round 5
// baseline (177.906 us; speedup 1.0000x reference)
//
#include <hip/hip_runtime.h>
#include <hip/hip_bf16.h>

#define B_ 2
#define L_ 2048
#define H_ 8
#define D_ 64
#define SP_ 65       // STRIDE+1
#define NC_ 128      // level-1 chunks (16 rows each)
#define NH_ 16       // level-2 chunks (128 rows each)
#define RS_ 512      // H_*D_ floats between consecutive seq rows
#define NPROD 324u   // producer blocks (260 strided + 64 csum)

typedef __attribute__((ext_vector_type(8))) short bf16x8;
typedef __attribute__((ext_vector_type(16))) float f32x16;

static __device__ inline short f2bf(float x) {
    return __builtin_bit_cast(short, __float2bfloat16(x));
}

static __device__ inline bf16x8 ld8_bf16(const float* __restrict__ p) {
    float4 a = *(const float4*)p;
    float4 b = *(const float4*)(p + 4);
    bf16x8 r;
    r[0]=f2bf(a.x); r[1]=f2bf(a.y); r[2]=f2bf(a.z); r[3]=f2bf(a.w);
    r[4]=f2bf(b.x); r[5]=f2bf(b.y); r[6]=f2bf(b.z); r[7]=f2bf(b.w);
    return r;
}

static __device__ inline bf16x8 ones_frag() {
    bf16x8 r;
    short o = f2bf(1.f);
    #pragma unroll
    for (int t = 0; t < 8; ++t) r[t] = o;
    return r;
}

// wave-level acquire-poll: lane 0 does the device-scope RMW, broadcasts;
// s_sleep backoff keeps issue slots free for producer waves on the same CU.
static __device__ inline void wait_flag(unsigned* flag, int lane) {
    unsigned done;
    do {
        unsigned f = 0;
        if (lane == 0) f = atomicAdd(flag, 0u);
        done = (unsigned)__shfl((int)f, 0);
        if (done < NPROD) __builtin_amdgcn_s_sleep(2);
    } while (done < NPROD);
    __threadfence();   // acquire: invalidate stale L1/L2 before reading pB/zB/csum
}

// ================= Single merged kernel, plain launch =======================
// Blocks 0..259  : strided residue units (4 waves/block, 1040 units) -> pB,zB
// Blocks 260..323: fused csum units (4 waves/block): 8 csum1 chunks + csumH
//                  per 128-row unit, single V pass.
//   each producer block ends with: syncthreads -> threadfence -> atomicAdd(flag)
// Blocks 324..835: local band tiles (2 teams/block, verbatim math). All
//   producer-independent work (V/Q/K fetch, QK^T, weights, PV MFMA) runs
//   BEFORE the flag poll; finalize (prefix + pB/zB + divide) after.
// Co-residency guarantee: 836 blocks, launch_bounds(256,4) => >=4 blocks/CU
// (VGPR<=128, LDS 18.7KB => 8/CU) => capacity 1024 >= 836; producers are the
// lowest block indices so they dispatch first. No launch boundary, no
// cooperative launch: graph-capture safe.
__global__ __launch_bounds__(256, 4) void dozer_k(const float* __restrict__ q,
                                                  const float* __restrict__ kk,
                                                  const float* __restrict__ v,
                                                  float* __restrict__ csum1,
                                                  float* __restrict__ csumH,
                                                  float* __restrict__ pB,
                                                  float* __restrict__ zB,
                                                  float* __restrict__ out,
                                                  unsigned* __restrict__ flag) {
    __shared__ float LDS[4672];  // strided: 4x[32][36]=4608 | local: 2x[32][68]+PF+ZW
    int wib  = threadIdx.x >> 6;
    int lane = threadIdx.x & 63;
    int half = lane >> 5, ln = lane & 31;
    int blk  = blockIdx.x;

    if (blk < 260) {
        // ---------- strided residue class mod 65: rows l = r + 65*s, s=0..31
        int us = blk * 4 + wib;          // 0..1039
        int bh = us / SP_;
        int r  = us % SP_;
        int h = bh & 7, b = bh >> 3;
        const size_t base = (size_t)b * L_ * RS_ + (size_t)h * D_;
        float* Pw = LDS + wib * 1152;    // [32][36]

        bf16x8 bv0[2], bv1[2];
        #pragma unroll
        for (int kb = 0; kb < 2; ++kb) {
            int k0 = kb * 16 + half * 8;
            #pragma unroll
            for (int jj = 0; jj < 8; ++jj) {
                int lv = r + SP_ * (k0 + jj);
                lv = lv > L_ - 1 ? L_ - 1 : lv;
                const float* vr = v + base + (size_t)lv * RS_;
                bv0[kb][jj] = f2bf(vr[ln]);
                bv1[kb][jj] = f2bf(vr[32 + ln]);
            }
        }

        int lq = r + SP_ * ln;
        int lqc = lq > L_ - 1 ? L_ - 1 : lq;
        const float* qrow = q  + base + (size_t)lqc * RS_;
        const float* krow = kk + base + (size_t)lqc * RS_;
        f32x16 acc = {};
        #pragma unroll
        for (int kb = 0; kb < 4; ++kb) {
            bf16x8 a  = ld8_bf16(qrow + kb * 16 + half * 8);
            bf16x8 bb = ld8_bf16(krow + kb * 16 + half * 8);
            acc = __builtin_amdgcn_mfma_f32_32x32x16_bf16(a, bb, acc, 0, 0, 0);
        }
        #pragma unroll
        for (int rg = 0; rg < 16; ++rg) {
            int m = (rg & 3) + 8 * (rg >> 2) + 4 * half;
            bool act = (ln < m) && (r + SP_ * m < L_);
            Pw[m * 36 + ln] = act ? (__expf(0.125f * acc[rg]) - 1.f) : 0.f;
        }
        __syncthreads();

        f32x16 p0 = {}; f32x16 p1 = {}; f32x16 po = {};
        bf16x8 ones = ones_frag();
        #pragma unroll
        for (int kb = 0; kb < 2; ++kb) {
            int k0 = kb * 16 + half * 8;
            const float* pr = &Pw[ln * 36 + k0];
            float4 x = *(const float4*)pr;
            float4 y = *(const float4*)(pr + 4);
            bf16x8 ap;
            ap[0]=f2bf(x.x); ap[1]=f2bf(x.y); ap[2]=f2bf(x.z); ap[3]=f2bf(x.w);
            ap[4]=f2bf(y.x); ap[5]=f2bf(y.y); ap[6]=f2bf(y.z); ap[7]=f2bf(y.w);
            p0 = __builtin_amdgcn_mfma_f32_32x32x16_bf16(ap, bv0[kb], p0, 0, 0, 0);
            p1 = __builtin_amdgcn_mfma_f32_32x32x16_bf16(ap, bv1[kb], p1, 0, 0, 0);
            po = __builtin_amdgcn_mfma_f32_32x32x16_bf16(ap, ones,    po, 0, 0, 0);
        }
        float* pBr = pB + (size_t)bh * L_ * D_;
        float* zBr = zB + (size_t)bh * L_;
        #pragma unroll
        for (int rg = 0; rg < 16; ++rg) {
            int m = (rg & 3) + 8 * (rg >> 2) + 4 * half;
            int l = r + SP_ * m;
            if (l < L_) {
                pBr[(size_t)l * D_ + ln]      = p0[rg];
                pBr[(size_t)l * D_ + 32 + ln] = p1[rg];
                if (ln == 0) zBr[l] = po[rg];
            }
        }
        // release: all 4 waves' writes drained by barrier, L2 flushed by fence
        __syncthreads();
        if (threadIdx.x == 0) { __threadfence(); atomicAdd(flag, 1u); }
    } else if (blk < 324) {
        // ---------- fused csum: one 128-row unit writes 8 csum1 + 1 csumH
        int uc = (blk - 260) * 4 + wib;  // 0..255 = bh*16 + cH
        int cH = uc & (NH_ - 1);
        int bh = uc >> 4;
        int h = bh & 7, b = bh >> 3;
        const float* vb = v + (size_t)(b * L_ + cH * 128) * RS_ + h * D_ + lane;
        float* c1p = csum1 + ((size_t)bh * NC_ + cH * 8) * D_ + lane;
        float hs = 0.f;
        #pragma unroll
        for (int c = 0; c < 8; ++c) {
            float s0 = 0.f, s1 = 0.f, s2 = 0.f, s3 = 0.f;
            #pragma unroll
            for (int l = 0; l < 16; l += 4) {
                s0 += vb[(c * 16 + l + 0) * RS_]; s1 += vb[(c * 16 + l + 1) * RS_];
                s2 += vb[(c * 16 + l + 2) * RS_]; s3 += vb[(c * 16 + l + 3) * RS_];
            }
            float s = (s0 + s1) + (s2 + s3);
            c1p[c * D_] = s;
            hs += s;
        }
        csumH[((size_t)bh * NH_ + cH) * D_ + lane] = hs;
        __syncthreads();
        if (threadIdx.x == 0) { __threadfence(); atomicAdd(flag, 1u); }
    } else {
        // ---------- consumer: local band tile + in-register finalize
        int cb = blk - 324;              // 0..511
        // XCD-chunked swizzle: contiguous tiles per XCD for K/V band L2 reuse
        int wid = (cb & 7) * 64 + (cb >> 3);

        int tb = wib >> 1;
        int hf = wib & 1;
        int team = wid * 2 + tb;         // 0..1023
        int bh = team >> 6;
        int T  = (team & 63) << 5;
        int h = bh & 7, b = bh >> 3;
        const size_t base = (size_t)b * L_ * RS_ + (size_t)h * D_;
        float* Pw = LDS + tb * 2176;         // [32][68]
        float* PF = LDS + 4352 + tb * 128;   // [2][64]: P0, P1
        float* ZW = LDS + 4608 + tb * 32;    // [32]: band z per row
        int d0 = 32 * hf;

        // V prefetch: band rows, this wave's dims [d0, d0+32)
        bf16x8 bv[4];
        #pragma unroll
        for (int kb = 0; kb < 4; ++kb) {
            #pragma unroll
            for (int jj = 0; jj < 8; ++jj) {
                int jr = T - 16 + kb * 16 + half * 8 + jj;
                jr = jr < 0 ? 0 : (jr > L_ - 1 ? L_ - 1 : jr);
                bv[kb][jj] = f2bf(v[base + (size_t)jr * RS_ + d0 + ln]);
            }
        }

        // QK^T for this wave's 32-col tile
        const float* qrow = q + base + (size_t)(T + ln) * RS_;
        bf16x8 aq[4];
        #pragma unroll
        for (int kb = 0; kb < 4; ++kb) aq[kb] = ld8_bf16(qrow + kb * 16 + half * 8);

        int j = T - 16 + d0 + ln;
        j = j < 0 ? 0 : (j > L_ - 1 ? L_ - 1 : j);
        const float* krow = kk + base + (size_t)j * RS_;
        f32x16 acc = {};
        #pragma unroll
        for (int kb = 0; kb < 4; ++kb) {
            bf16x8 kf = ld8_bf16(krow + kb * 16 + half * 8);
            acc = __builtin_amdgcn_mfma_f32_32x32x16_bf16(aq[kb], kf, acc, 0, 0, 0);
        }

        // weights (exp-1 masked + "+1" prefix fold) into this wave's col half
        #pragma unroll
        for (int r = 0; r < 16; ++r) {
            int m = (r & 3) + 8 * (r >> 2) + 4 * half;
            float w;
            if (hf == 0) {
                bool act = (ln >= m) && (ln <= m + 16) && (T - 16 + ln >= 0);
                w = act ? (__expf(0.125f * acc[r]) - 1.f) : 0.f;
                if ((m < 16) && (ln >= 16) && (ln <= m + 16)) w += 1.f;
            } else {
                bool act = (ln <= m - 16);
                w = act ? (__expf(0.125f * acc[r]) - 1.f) : 0.f;
                if ((m >= 16) && (ln <= m - 16)) w += 1.f;
            }
            Pw[m * 68 + d0 + ln] = w;
        }
        __syncthreads();   // bar1: both halves' weights visible

        // PV over full 64-col band (producer-independent -> before the poll)
        f32x16 p = {}; f32x16 po = {};
        bf16x8 ones = ones_frag();
        #pragma unroll
        for (int kb = 0; kb < 4; ++kb) {
            int k0 = kb * 16 + half * 8;
            const float* pr = &Pw[ln * 68 + k0];
            float4 x = *(const float4*)pr;
            float4 y = *(const float4*)(pr + 4);
            bf16x8 ap;
            ap[0]=f2bf(x.x); ap[1]=f2bf(x.y); ap[2]=f2bf(x.z); ap[3]=f2bf(x.w);
            ap[4]=f2bf(y.x); ap[5]=f2bf(y.y); ap[6]=f2bf(y.z); ap[7]=f2bf(y.w);
            p = __builtin_amdgcn_mfma_f32_32x32x16_bf16(ap, bv[kb], p, 0, 0, 0);
            if (hf == 1)
                po = __builtin_amdgcn_mfma_f32_32x32x16_bf16(ap, ones, po, 0, 0, 0);
        }

        // ---- producers must be done past this point ----
        wait_flag(flag, lane);

        // hf==0: hierarchical prefix for this tile; hf==1: publish band z
        if (hf == 0) {
            int c1 = T >> 4;             // 16-row chunks below T (0..126)
            int nH = c1 >> 3, nR = c1 & 7;
            const float* csH = csumH + (size_t)bh * NH_ * D_ + lane;
            const float* cs1 = csum1 + ((size_t)bh * NC_ + (c1 & ~7)) * D_ + lane;
            float s0 = 0.f, s1 = 0.f, s2 = 0.f, s3 = 0.f;
            int cc = 0;
            for (; cc + 4 <= nH; cc += 4) {
                s0 += csH[(cc + 0) * D_]; s1 += csH[(cc + 1) * D_];
                s2 += csH[(cc + 2) * D_]; s3 += csH[(cc + 3) * D_];
            }
            for (; cc < nH; ++cc) s0 += csH[cc * D_];
            for (int t = 0; t < nR; ++t) {
                if (t & 1) s1 += cs1[t * D_]; else s2 += cs1[t * D_];
            }
            float P0 = (s0 + s1) + (s2 + s3);
            float P1 = P0 + csum1[((size_t)bh * NC_ + c1) * D_ + lane];
            PF[lane]      = P0;
            PF[64 + lane] = P1;
        } else {
            #pragma unroll
            for (int r = 0; r < 16; ++r) {
                int m = (r & 3) + 8 * (r >> 2) + 4 * half;
                if (ln == 0) ZW[m] = po[r] - (float)((m & 15) + 1);
            }
        }

        // pB/zB prefetch for this wave's rows (L2/L3-hot from producers)
        const float* pBr = pB + (size_t)bh * L_ * D_;
        const float* zBr = zB + (size_t)bh * L_;
        float pbv[16], zbv[16];
        #pragma unroll
        for (int r = 0; r < 16; ++r) {
            int m = (r & 3) + 8 * (r >> 2) + 4 * half;
            int i = T + m;
            pbv[r] = pBr[(size_t)i * D_ + d0 + ln];
            zbv[r] = zBr[i];
        }
        __syncthreads();   // bar2: PF + ZW visible

        // finalize: out = (band + strided + prefix) / z
        float Pf0 = PF[d0 + ln];
        float Pf1 = PF[64 + d0 + ln];
        #pragma unroll
        for (int r = 0; r < 16; ++r) {
            int m = (r & 3) + 8 * (r >> 2) + 4 * half;
            int i = T + m;
            float z   = ZW[m] + zbv[r] + (float)(i + 1);
            float num = p[r] + pbv[r] + (m < 16 ? Pf0 : Pf1);
            out[base + (size_t)i * RS_ + d0 + ln] = num / z;
        }
    }
}

extern "C" void kernel_launch(void* const* d_in, const int* in_sizes, int n_in,
                              void* d_out, int out_size, void* d_ws, size_t ws_size,
                              hipStream_t stream) {
    const float* q = (const float*)d_in[0];
    const float* k = (const float*)d_in[1];
    const float* v = (const float*)d_in[2];
    // d_in[3] = attn_mask: deterministic causal — not read.
    float* out = (float*)d_out;

    float* csum1 = (float*)d_ws;                          // 131072 f
    float* pB    = csum1 + (size_t)B_ * H_ * NC_ * D_;    // 2097152 f
    float* zB    = pB    + (size_t)B_ * H_ * L_ * D_;     // 32768 f
    float* csumH = zB    + (size_t)B_ * H_ * L_;          // 16384 f
    unsigned* flag = (unsigned*)(csumH + (size_t)B_ * H_ * NH_ * D_);

    // workspace is poisoned between iterations -> zero the flag (capturable)
    hipMemsetAsync(flag, 0, sizeof(unsigned), stream);
    // 260 strided + 64 csum producers, then 512 consumer blocks; 836 < 1024
    // guaranteed-resident at 4 blocks/CU.
    dozer_k<<<836, 256, 0, stream>>>(q, k, v, csum1, csumH, pB, zB, out, flag);
}

// Round 6
// 172.435 us; speedup vs baseline: 1.0317x; 1.0317x over previous
//
#include <hip/hip_runtime.h>
#include <hip/hip_bf16.h>

#define B_ 2
#define L_ 2048
#define H_ 8
#define D_ 64
#define SP_ 65       // STRIDE+1
#define NC_ 128      // level-1 chunks (16 rows each)
#define NH_ 16       // level-2 chunks (128 rows each)
#define RS_ 512      // H_*D_ floats between consecutive seq rows
#define NPROD 324u   // producer blocks (260 strided + 64 csum)

typedef __attribute__((ext_vector_type(8))) short bf16x8;
typedef __attribute__((ext_vector_type(16))) float f32x16;

static __device__ inline short f2bf(float x) {
    return __builtin_bit_cast(short, __float2bfloat16(x));
}

static __device__ inline bf16x8 ld8_bf16(const float* __restrict__ p) {
    float4 a = *(const float4*)p;
    float4 b = *(const float4*)(p + 4);
    bf16x8 r;
    r[0]=f2bf(a.x); r[1]=f2bf(a.y); r[2]=f2bf(a.z); r[3]=f2bf(a.w);
    r[4]=f2bf(b.x); r[5]=f2bf(b.y); r[6]=f2bf(b.z); r[7]=f2bf(b.w);
    return r;
}

static __device__ inline bf16x8 ones_frag() {
    bf16x8 r;
    short o = f2bf(1.f);
    #pragma unroll
    for (int t = 0; t < 8; ++t) r[t] = o;
    return r;
}

// ================= Single merged kernel, plain launch =======================
// Blocks 0..259  : strided residue units (4 waves/block, 1040 units) -> pB,zB
// Blocks 260..323: fused csum units: 8 csum1 chunks + csumH per 128-row unit.
//   producer release: __syncthreads -> __threadfence -> atomicAdd(flag,1)
// Blocks 324..835: local band tiles (2 teams/block). Producer-independent
//   work (V/Q/K fetch, QK^T, weights, PV MFMA, ZW publish) runs BEFORE the
//   flag poll. POLL IS AN ATOMIC LOAD BY ONE WAVE PER BLOCK (round-5 lesson:
//   2048 waves spinning on atomicAdd RMW serialized the flag line and
//   stretched the kernel to 102us; loads don't serialize).
// Co-residency: 836 blocks, LDS 18.7KB (8/CU), VGPR<=128 -> capacity >= 4/CU
// = 1024 >= 836; producers are lowest block indices so they dispatch first.
__global__ __launch_bounds__(256, 4) void dozer_k(const float* __restrict__ q,
                                                  const float* __restrict__ kk,
                                                  const float* __restrict__ v,
                                                  float* __restrict__ csum1,
                                                  float* __restrict__ csumH,
                                                  float* __restrict__ pB,
                                                  float* __restrict__ zB,
                                                  float* __restrict__ out,
                                                  unsigned* __restrict__ flag) {
    __shared__ float LDS[4672];  // strided: 4x[32][36]=4608 | local: 2x[32][68]+PF+ZW
    int wib  = threadIdx.x >> 6;
    int lane = threadIdx.x & 63;
    int half = lane >> 5, ln = lane & 31;
    int blk  = blockIdx.x;

    if (blk < 260) {
        // ---------- strided residue class mod 65: rows l = r + 65*s, s=0..31
        int us = blk * 4 + wib;          // 0..1039
        int bh = us / SP_;
        int r  = us % SP_;
        int h = bh & 7, b = bh >> 3;
        const size_t base = (size_t)b * L_ * RS_ + (size_t)h * D_;
        float* Pw = LDS + wib * 1152;    // [32][36]

        bf16x8 bv0[2], bv1[2];
        #pragma unroll
        for (int kb = 0; kb < 2; ++kb) {
            int k0 = kb * 16 + half * 8;
            #pragma unroll
            for (int jj = 0; jj < 8; ++jj) {
                int lv = r + SP_ * (k0 + jj);
                lv = lv > L_ - 1 ? L_ - 1 : lv;
                const float* vr = v + base + (size_t)lv * RS_;
                bv0[kb][jj] = f2bf(vr[ln]);
                bv1[kb][jj] = f2bf(vr[32 + ln]);
            }
        }

        int lq = r + SP_ * ln;
        int lqc = lq > L_ - 1 ? L_ - 1 : lq;
        const float* qrow = q  + base + (size_t)lqc * RS_;
        const float* krow = kk + base + (size_t)lqc * RS_;
        f32x16 acc = {};
        #pragma unroll
        for (int kb = 0; kb < 4; ++kb) {
            bf16x8 a  = ld8_bf16(qrow + kb * 16 + half * 8);
            bf16x8 bb = ld8_bf16(krow + kb * 16 + half * 8);
            acc = __builtin_amdgcn_mfma_f32_32x32x16_bf16(a, bb, acc, 0, 0, 0);
        }
        #pragma unroll
        for (int rg = 0; rg < 16; ++rg) {
            int m = (rg & 3) + 8 * (rg >> 2) + 4 * half;
            bool act = (ln < m) && (r + SP_ * m < L_);
            Pw[m * 36 + ln] = act ? (__expf(0.125f * acc[rg]) - 1.f) : 0.f;
        }
        __syncthreads();

        f32x16 p0 = {}; f32x16 p1 = {}; f32x16 po = {};
        bf16x8 ones = ones_frag();
        #pragma unroll
        for (int kb = 0; kb < 2; ++kb) {
            int k0 = kb * 16 + half * 8;
            const float* pr = &Pw[ln * 36 + k0];
            float4 x = *(const float4*)pr;
            float4 y = *(const float4*)(pr + 4);
            bf16x8 ap;
            ap[0]=f2bf(x.x); ap[1]=f2bf(x.y); ap[2]=f2bf(x.z); ap[3]=f2bf(x.w);
            ap[4]=f2bf(y.x); ap[5]=f2bf(y.y); ap[6]=f2bf(y.z); ap[7]=f2bf(y.w);
            p0 = __builtin_amdgcn_mfma_f32_32x32x16_bf16(ap, bv0[kb], p0, 0, 0, 0);
            p1 = __builtin_amdgcn_mfma_f32_32x32x16_bf16(ap, bv1[kb], p1, 0, 0, 0);
            po = __builtin_amdgcn_mfma_f32_32x32x16_bf16(ap, ones,    po, 0, 0, 0);
        }
        float* pBr = pB + (size_t)bh * L_ * D_;
        float* zBr = zB + (size_t)bh * L_;
        #pragma unroll
        for (int rg = 0; rg < 16; ++rg) {
            int m = (rg & 3) + 8 * (rg >> 2) + 4 * half;
            int l = r + SP_ * m;
            if (l < L_) {
                pBr[(size_t)l * D_ + ln]      = p0[rg];
                pBr[(size_t)l * D_ + 32 + ln] = p1[rg];
                if (ln == 0) zBr[l] = po[rg];
            }
        }
        // release: barrier drains all waves' writes to L2; fence writes back
        __syncthreads();
        if (threadIdx.x == 0) { __threadfence(); atomicAdd(flag, 1u); }
    } else if (blk < 324) {
        // ---------- fused csum: one 128-row unit writes 8 csum1 + 1 csumH
        int uc = (blk - 260) * 4 + wib;  // 0..255 = bh*16 + cH
        int cH = uc & (NH_ - 1);
        int bh = uc >> 4;
        int h = bh & 7, b = bh >> 3;
        const float* vb = v + (size_t)(b * L_ + cH * 128) * RS_ + h * D_ + lane;
        float* c1p = csum1 + ((size_t)bh * NC_ + cH * 8) * D_ + lane;
        float hs = 0.f;
        #pragma unroll
        for (int c = 0; c < 8; ++c) {
            float s0 = 0.f, s1 = 0.f, s2 = 0.f, s3 = 0.f;
            #pragma unroll
            for (int l = 0; l < 16; l += 4) {
                s0 += vb[(c * 16 + l + 0) * RS_]; s1 += vb[(c * 16 + l + 1) * RS_];
                s2 += vb[(c * 16 + l + 2) * RS_]; s3 += vb[(c * 16 + l + 3) * RS_];
            }
            float s = (s0 + s1) + (s2 + s3);
            c1p[c * D_] = s;
            hs += s;
        }
        csumH[((size_t)bh * NH_ + cH) * D_ + lane] = hs;
        __syncthreads();
        if (threadIdx.x == 0) { __threadfence(); atomicAdd(flag, 1u); }
    } else {
        // ---------- consumer: local band tile + in-register finalize
        int cb = blk - 324;              // 0..511
        // XCD-chunked swizzle: contiguous tiles per XCD for K/V band L2 reuse
        int wid = (cb & 7) * 64 + (cb >> 3);

        int tb = wib >> 1;
        int hf = wib & 1;
        int team = wid * 2 + tb;         // 0..1023
        int bh = team >> 6;
        int T  = (team & 63) << 5;
        int h = bh & 7, b = bh >> 3;
        const size_t base = (size_t)b * L_ * RS_ + (size_t)h * D_;
        float* Pw = LDS + tb * 2176;         // [32][68]
        float* PF = LDS + 4352 + tb * 128;   // [2][64]: P0, P1
        float* ZW = LDS + 4608 + tb * 32;    // [32]: band z per row
        int d0 = 32 * hf;

        // V prefetch: band rows, this wave's dims [d0, d0+32)
        bf16x8 bv[4];
        #pragma unroll
        for (int kb = 0; kb < 4; ++kb) {
            #pragma unroll
            for (int jj = 0; jj < 8; ++jj) {
                int jr = T - 16 + kb * 16 + half * 8 + jj;
                jr = jr < 0 ? 0 : (jr > L_ - 1 ? L_ - 1 : jr);
                bv[kb][jj] = f2bf(v[base + (size_t)jr * RS_ + d0 + ln]);
            }
        }

        // QK^T for this wave's 32-col tile
        const float* qrow = q + base + (size_t)(T + ln) * RS_;
        bf16x8 aq[4];
        #pragma unroll
        for (int kb = 0; kb < 4; ++kb) aq[kb] = ld8_bf16(qrow + kb * 16 + half * 8);

        int j = T - 16 + d0 + ln;
        j = j < 0 ? 0 : (j > L_ - 1 ? L_ - 1 : j);
        const float* krow = kk + base + (size_t)j * RS_;
        f32x16 acc = {};
        #pragma unroll
        for (int kb = 0; kb < 4; ++kb) {
            bf16x8 kf = ld8_bf16(krow + kb * 16 + half * 8);
            acc = __builtin_amdgcn_mfma_f32_32x32x16_bf16(aq[kb], kf, acc, 0, 0, 0);
        }

        // weights (exp-1 masked + "+1" prefix fold) into this wave's col half
        #pragma unroll
        for (int r = 0; r < 16; ++r) {
            int m = (r & 3) + 8 * (r >> 2) + 4 * half;
            float w;
            if (hf == 0) {
                bool act = (ln >= m) && (ln <= m + 16) && (T - 16 + ln >= 0);
                w = act ? (__expf(0.125f * acc[r]) - 1.f) : 0.f;
                if ((m < 16) && (ln >= 16) && (ln <= m + 16)) w += 1.f;
            } else {
                bool act = (ln <= m - 16);
                w = act ? (__expf(0.125f * acc[r]) - 1.f) : 0.f;
                if ((m >= 16) && (ln <= m - 16)) w += 1.f;
            }
            Pw[m * 68 + d0 + ln] = w;
        }
        __syncthreads();   // bar1: both halves' weights visible

        // PV over full 64-col band (producer-independent -> before the poll)
        f32x16 p = {}; f32x16 po = {};
        bf16x8 ones = ones_frag();
        #pragma unroll
        for (int kb = 0; kb < 4; ++kb) {
            int k0 = kb * 16 + half * 8;
            const float* pr = &Pw[ln * 68 + k0];
            float4 x = *(const float4*)pr;
            float4 y = *(const float4*)(pr + 4);
            bf16x8 ap;
            ap[0]=f2bf(x.x); ap[1]=f2bf(x.y); ap[2]=f2bf(x.z); ap[3]=f2bf(x.w);
            ap[4]=f2bf(y.x); ap[5]=f2bf(y.y); ap[6]=f2bf(y.z); ap[7]=f2bf(y.w);
            p = __builtin_amdgcn_mfma_f32_32x32x16_bf16(ap, bv[kb], p, 0, 0, 0);
            if (hf == 1)
                po = __builtin_amdgcn_mfma_f32_32x32x16_bf16(ap, ones, po, 0, 0, 0);
        }

        // ZW publish is producer-independent: do it before the poll
        if (hf == 1) {
            #pragma unroll
            for (int r = 0; r < 16; ++r) {
                int m = (r & 3) + 8 * (r >> 2) + 4 * half;
                if (ln == 0) ZW[m] = po[r] - (float)((m & 15) + 1);
            }
        }

        // ---- single-wave ATOMIC-LOAD poll (no RMW -> no serialization) ----
        if (wib == 0) {
            unsigned f;
            do {
                f = __hip_atomic_load(flag, __ATOMIC_RELAXED,
                                      __HIP_MEMORY_SCOPE_AGENT);
                if (f < NPROD) __builtin_amdgcn_s_sleep(8);
            } while (f < NPROD);
        }
        __syncthreads();   // bar2: poll complete + ZW visible to team partner
        __threadfence();   // acquire: discard stale cached csum/pB/zB

        // hf==0: hierarchical prefix for this tile (2 values x 64 dims)
        if (hf == 0) {
            int c1 = T >> 4;             // 16-row chunks below T (0..126)
            int nH = c1 >> 3, nR = c1 & 7;
            const float* csH = csumH + (size_t)bh * NH_ * D_ + lane;
            const float* cs1 = csum1 + ((size_t)bh * NC_ + (c1 & ~7)) * D_ + lane;
            float s0 = 0.f, s1 = 0.f, s2 = 0.f, s3 = 0.f;
            int cc = 0;
            for (; cc + 4 <= nH; cc += 4) {
                s0 += csH[(cc + 0) * D_]; s1 += csH[(cc + 1) * D_];
                s2 += csH[(cc + 2) * D_]; s3 += csH[(cc + 3) * D_];
            }
            for (; cc < nH; ++cc) s0 += csH[cc * D_];
            for (int t = 0; t < nR; ++t) {
                if (t & 1) s1 += cs1[t * D_]; else s2 += cs1[t * D_];
            }
            float P0 = (s0 + s1) + (s2 + s3);
            float P1 = P0 + csum1[((size_t)bh * NC_ + c1) * D_ + lane];
            PF[lane]      = P0;
            PF[64 + lane] = P1;
        }

        // pB/zB prefetch for this wave's rows (L2/L3-hot from producers)
        const float* pBr = pB + (size_t)bh * L_ * D_;
        const float* zBr = zB + (size_t)bh * L_;
        float pbv[16], zbv[16];
        #pragma unroll
        for (int r = 0; r < 16; ++r) {
            int m = (r & 3) + 8 * (r >> 2) + 4 * half;
            int i = T + m;
            pbv[r] = pBr[(size_t)i * D_ + d0 + ln];
            zbv[r] = zBr[i];
        }
        __syncthreads();   // bar3: PF visible

        // finalize: out = (band + strided + prefix) / z
        float Pf0 = PF[d0 + ln];
        float Pf1 = PF[64 + d0 + ln];
        #pragma unroll
        for (int r = 0; r < 16; ++r) {
            int m = (r & 3) + 8 * (r >> 2) + 4 * half;
            int i = T + m;
            float z   = ZW[m] + zbv[r] + (float)(i + 1);
            float num = p[r] + pbv[r] + (m < 16 ? Pf0 : Pf1);
            out[base + (size_t)i * RS_ + d0 + ln] = num / z;
        }
    }
}

extern "C" void kernel_launch(void* const* d_in, const int* in_sizes, int n_in,
                              void* d_out, int out_size, void* d_ws, size_t ws_size,
                              hipStream_t stream) {
    const float* q = (const float*)d_in[0];
    const float* k = (const float*)d_in[1];
    const float* v = (const float*)d_in[2];
    // d_in[3] = attn_mask: deterministic causal — not read.
    float* out = (float*)d_out;

    float* csum1 = (float*)d_ws;                          // 131072 f
    float* pB    = csum1 + (size_t)B_ * H_ * NC_ * D_;    // 2097152 f
    float* zB    = pB    + (size_t)B_ * H_ * L_ * D_;     // 32768 f
    float* csumH = zB    + (size_t)B_ * H_ * L_;          // 16384 f
    unsigned* flag = (unsigned*)(csumH + (size_t)B_ * H_ * NH_ * D_);

    // workspace is poisoned between iterations -> zero the flag (capturable)
    hipMemsetAsync(flag, 0, sizeof(unsigned), stream);
    // 260 strided + 64 csum producers, then 512 consumer blocks; 836 <= 1024
    // resident at 4 blocks/CU.
    dozer_k<<<836, 256, 0, stream>>>(q, k, v, csum1, csumH, pB, zB, out, flag);
}

// Round 7
// 108.682 us; speedup vs baseline: 1.6369x; 1.5866x over previous
//
#include <hip/hip_runtime.h>
#include <hip/hip_bf16.h>

#define B_ 2
#define L_ 2048
#define H_ 8
#define D_ 64
#define SP_ 65       // STRIDE+1
#define NC_ 128      // level-1 chunks (16 rows each)
#define NH_ 16       // level-2 chunks (128 rows each)
#define RS_ 512      // H_*D_ floats between consecutive seq rows

typedef __attribute__((ext_vector_type(8))) short bf16x8;
typedef __attribute__((ext_vector_type(16))) float f32x16;

static __device__ inline short f2bf(float x) {
    return __builtin_bit_cast(short, __float2bfloat16(x));
}

static __device__ inline bf16x8 ones_frag() {
    bf16x8 r;
    short o = f2bf(1.f);
    #pragma unroll
    for (int t = 0; t < 8; ++t) r[t] = o;
    return r;
}

// ================= Launch A: strided residue units + fused csum =============
// blk < 260 : strided residue units (4 waves/block, 1040 units) -> pB, zB
//   Q/K rows gathered COALESCED (4 rows/inst) into bf16 LDS with XOR swizzle,
//   then MFMA fragments via ds_read_b128 (was: 64-scattered-line ld8_bf16).
// blk < 324 : fused csum units (4 waves/block, 256 units): each 128-row unit
//             writes its 8 csum1 chunks AND csumH (single V pass).
__global__ __launch_bounds__(256) void pre_k(const float* __restrict__ q,
                                             const float* __restrict__ kk,
                                             const float* __restrict__ v,
                                             float* __restrict__ csum1,
                                             float* __restrict__ csumH,
                                             float* __restrict__ pB,
                                             float* __restrict__ zB) {
    // per unit: Qst 1024f (4KB bf16) | Kst 1024f | Pw [32][36] 1152f = 3200f
    __shared__ float LDS[12800];
    int wib  = threadIdx.x >> 6;
    int lane = threadIdx.x & 63;
    int half = lane >> 5, ln = lane & 31;
    int blk  = blockIdx.x;

    if (blk < 260) {
        // ---------- strided residue class mod 65: rows l = r + 65*s, s=0..31
        int us = blk * 4 + wib;          // 0..1039
        int bh = us / SP_;
        int r  = us % SP_;
        int h = bh & 7, b = bh >> 3;
        const size_t base = (size_t)b * L_ * RS_ + (size_t)h * D_;
        float* Ub  = LDS + wib * 3200;
        char* QstB = (char*)Ub;          // 4096 B
        char* KstB = (char*)Ub + 4096;   // 4096 B
        float* Pw  = Ub + 2048;          // [32][36]

        // V prefetch first (overlaps the staging): rows lv, 128B coalesced
        bf16x8 bv0[2], bv1[2];
        #pragma unroll
        for (int kb = 0; kb < 2; ++kb) {
            int k0 = kb * 16 + half * 8;
            #pragma unroll
            for (int jj = 0; jj < 8; ++jj) {
                int lv = r + SP_ * (k0 + jj);
                lv = lv > L_ - 1 ? L_ - 1 : lv;
                const float* vr = v + base + (size_t)lv * RS_;
                bv0[kb][jj] = f2bf(vr[ln]);
                bv1[kb][jj] = f2bf(vr[32 + ln]);
            }
        }

        // coalesced Q/K staging: 4 rows/inst (16 lanes x 16B = one 256B row)
        int rsub = lane >> 4, colf = (lane & 15) << 2, bytecol = (lane & 15) << 3;
        #pragma unroll
        for (int g = 0; g < 8; ++g) {
            int br = g * 4 + rsub;                  // staged row 0..31
            int gr = r + SP_ * br;
            gr = gr > L_ - 1 ? L_ - 1 : gr;
            float4 xq = *(const float4*)(q  + base + (size_t)gr * RS_ + colf);
            float4 xk = *(const float4*)(kk + base + (size_t)gr * RS_ + colf);
            int sw = br * 128 + (bytecol ^ ((br & 7) << 4));
            short4 hq = { f2bf(xq.x), f2bf(xq.y), f2bf(xq.z), f2bf(xq.w) };
            short4 hk = { f2bf(xk.x), f2bf(xk.y), f2bf(xk.z), f2bf(xk.w) };
            *(short4*)(QstB + sw) = hq;
            *(short4*)(KstB + sw) = hk;
        }
        // same-wave ds_write -> ds_read: compiler inserts lgkmcnt

        f32x16 acc = {};
        #pragma unroll
        for (int kb = 0; kb < 4; ++kb) {
            int bc = kb * 32 + half * 16;
            int off = ln * 128 + (bc ^ ((ln & 7) << 4));
            bf16x8 a  = *(const bf16x8*)(QstB + off);
            bf16x8 bb = *(const bf16x8*)(KstB + off);
            acc = __builtin_amdgcn_mfma_f32_32x32x16_bf16(a, bb, acc, 0, 0, 0);
        }
        #pragma unroll
        for (int rg = 0; rg < 16; ++rg) {
            int m = (rg & 3) + 8 * (rg >> 2) + 4 * half;
            bool act = (ln < m) && (r + SP_ * m < L_);
            Pw[m * 36 + ln] = act ? (__expf(0.125f * acc[rg]) - 1.f) : 0.f;
        }
        __syncthreads();

        f32x16 p0 = {}; f32x16 p1 = {}; f32x16 po = {};
        bf16x8 ones = ones_frag();
        #pragma unroll
        for (int kb = 0; kb < 2; ++kb) {
            int k0 = kb * 16 + half * 8;
            const float* pr = &Pw[ln * 36 + k0];
            float4 x = *(const float4*)pr;
            float4 y = *(const float4*)(pr + 4);
            bf16x8 ap;
            ap[0]=f2bf(x.x); ap[1]=f2bf(x.y); ap[2]=f2bf(x.z); ap[3]=f2bf(x.w);
            ap[4]=f2bf(y.x); ap[5]=f2bf(y.y); ap[6]=f2bf(y.z); ap[7]=f2bf(y.w);
            p0 = __builtin_amdgcn_mfma_f32_32x32x16_bf16(ap, bv0[kb], p0, 0, 0, 0);
            p1 = __builtin_amdgcn_mfma_f32_32x32x16_bf16(ap, bv1[kb], p1, 0, 0, 0);
            po = __builtin_amdgcn_mfma_f32_32x32x16_bf16(ap, ones,    po, 0, 0, 0);
        }
        float* pBr = pB + (size_t)bh * L_ * D_;
        float* zBr = zB + (size_t)bh * L_;
        #pragma unroll
        for (int rg = 0; rg < 16; ++rg) {
            int m = (rg & 3) + 8 * (rg >> 2) + 4 * half;
            int l = r + SP_ * m;
            if (l < L_) {
                pBr[(size_t)l * D_ + ln]      = p0[rg];
                pBr[(size_t)l * D_ + 32 + ln] = p1[rg];
                if (ln == 0) zBr[l] = po[rg];
            }
        }
    } else {
        // ---------- fused csum: one 128-row unit writes 8 csum1 + 1 csumH
        int uc = (blk - 260) * 4 + wib;  // 0..255 = bh*16 + cH
        int cH = uc & (NH_ - 1);
        int bh = uc >> 4;
        int h = bh & 7, b = bh >> 3;
        const float* vb = v + (size_t)(b * L_ + cH * 128) * RS_ + h * D_ + lane;
        float* c1p = csum1 + ((size_t)bh * NC_ + cH * 8) * D_ + lane;
        float hs = 0.f;
        #pragma unroll
        for (int c = 0; c < 8; ++c) {
            float s0 = 0.f, s1 = 0.f, s2 = 0.f, s3 = 0.f;
            #pragma unroll
            for (int l = 0; l < 16; l += 4) {
                s0 += vb[(c * 16 + l + 0) * RS_]; s1 += vb[(c * 16 + l + 1) * RS_];
                s2 += vb[(c * 16 + l + 2) * RS_]; s3 += vb[(c * 16 + l + 3) * RS_];
            }
            float s = (s0 + s1) + (s2 + s3);
            c1p[c * D_] = s;
            hs += s;
        }
        csumH[((size_t)bh * NH_ + cH) * D_ + lane] = hs;
    }
}

// ================= Launch B: local band MFMA + in-register finalize =========
// 512 blocks x 2 teams: team = local 32-row tile. Q (shared by both waves,
// staged once) and the 64-row K band are gathered coalesced into bf16 LDS
// with XOR swizzle; fragments via ds_read_b128. Finalize fused as round 4.
__global__ __launch_bounds__(256) void local_k(const float* __restrict__ q,
                                               const float* __restrict__ kk,
                                               const float* __restrict__ v,
                                               const float* __restrict__ csum1,
                                               const float* __restrict__ csumH,
                                               const float* __restrict__ pB,
                                               const float* __restrict__ zB,
                                               float* __restrict__ out) {
    // per team: Kst 2048f (8KB bf16, 64 rows) | Qst 1024f (32 rows) |
    //           Pw [32][68] 2176f | PF [2][64] 128f | ZW [32] 32f = 5408f
    __shared__ float LDS[10816];
    int wib  = threadIdx.x >> 6;
    int lane = threadIdx.x & 63;
    int half = lane >> 5, ln = lane & 31;
    // XCD-chunked swizzle (512 = 8 XCDs x 64): contiguous tiles per XCD
    int wid = (blockIdx.x & 7) * 64 + (blockIdx.x >> 3);

    int tb = wib >> 1;
    int hf = wib & 1;
    int team = wid * 2 + tb;             // 0..1023
    int bh = team >> 6;
    int T  = (team & 63) << 5;
    int h = bh & 7, b = bh >> 3;
    const size_t base = (size_t)b * L_ * RS_ + (size_t)h * D_;
    float* Tm  = LDS + tb * 5408;
    char* KstB = (char*)Tm;              // 8192 B: band rows 0..63
    char* QstB = (char*)Tm + 8192;       // 4096 B: Q rows 0..31
    float* Pw  = Tm + 3072;              // [32][68]
    float* PF  = Tm + 5248;              // [2][64]
    float* ZW  = Tm + 5376;              // [32]
    int d0 = 32 * hf;

    // V prefetch first (overlaps staging): 2 rows x 128B per inst
    bf16x8 bv[4];
    #pragma unroll
    for (int kb = 0; kb < 4; ++kb) {
        #pragma unroll
        for (int jj = 0; jj < 8; ++jj) {
            int jr = T - 16 + kb * 16 + half * 8 + jj;
            jr = jr < 0 ? 0 : (jr > L_ - 1 ? L_ - 1 : jr);
            bv[kb][jj] = f2bf(v[base + (size_t)jr * RS_ + d0 + ln]);
        }
    }

    // coalesced staging: K band rows [d0, d0+32) (own fragment rows) +
    // Q rows [hf*16, hf*16+16) (team-shared, deduped across waves)
    int rsub = lane >> 4, colf = (lane & 15) << 2, bytecol = (lane & 15) << 3;
    #pragma unroll
    for (int g = 0; g < 8; ++g) {
        int br = d0 + g * 4 + rsub;                 // band row 0..63
        int gr = T - 16 + br;
        gr = gr < 0 ? 0 : (gr > L_ - 1 ? L_ - 1 : gr);
        float4 x = *(const float4*)(kk + base + (size_t)gr * RS_ + colf);
        short4 hb = { f2bf(x.x), f2bf(x.y), f2bf(x.z), f2bf(x.w) };
        *(short4*)(KstB + br * 128 + (bytecol ^ ((br & 7) << 4))) = hb;
    }
    #pragma unroll
    for (int g = 0; g < 4; ++g) {
        int br = hf * 16 + g * 4 + rsub;            // Q row 0..31
        float4 x = *(const float4*)(q + base + (size_t)(T + br) * RS_ + colf);
        short4 hb = { f2bf(x.x), f2bf(x.y), f2bf(x.z), f2bf(x.w) };
        *(short4*)(QstB + br * 128 + (bytecol ^ ((br & 7) << 4))) = hb;
    }
    __syncthreads();   // bar0: staged Q (cross-wave) + K visible

    // QK^T from LDS fragments
    f32x16 acc = {};
    #pragma unroll
    for (int kb = 0; kb < 4; ++kb) {
        int bc = kb * 32 + half * 16;
        bf16x8 a  = *(const bf16x8*)(QstB + ln * 128 + (bc ^ ((ln & 7) << 4)));
        int kr = d0 + ln;
        bf16x8 kf = *(const bf16x8*)(KstB + kr * 128 + (bc ^ ((kr & 7) << 4)));
        acc = __builtin_amdgcn_mfma_f32_32x32x16_bf16(a, kf, acc, 0, 0, 0);
    }

    // weights (exp-1 masked + "+1" prefix fold) into this wave's col half
    #pragma unroll
    for (int r = 0; r < 16; ++r) {
        int m = (r & 3) + 8 * (r >> 2) + 4 * half;
        float w;
        if (hf == 0) {
            bool act = (ln >= m) && (ln <= m + 16) && (T - 16 + ln >= 0);
            w = act ? (__expf(0.125f * acc[r]) - 1.f) : 0.f;
            if ((m < 16) && (ln >= 16) && (ln <= m + 16)) w += 1.f;
        } else {
            bool act = (ln <= m - 16);
            w = act ? (__expf(0.125f * acc[r]) - 1.f) : 0.f;
            if ((m >= 16) && (ln <= m - 16)) w += 1.f;
        }
        Pw[m * 68 + d0 + ln] = w;
    }

    // hf==0 wave: hierarchical prefix for this tile (2 values x 64 dims)
    if (hf == 0) {
        int c1 = T >> 4;                 // 16-row chunks below T (0..126)
        int nH = c1 >> 3, nR = c1 & 7;
        const float* csH = csumH + (size_t)bh * NH_ * D_ + lane;
        const float* cs1 = csum1 + ((size_t)bh * NC_ + (c1 & ~7)) * D_ + lane;
        float s0 = 0.f, s1 = 0.f, s2 = 0.f, s3 = 0.f;
        int cc = 0;
        for (; cc + 4 <= nH; cc += 4) {
            s0 += csH[(cc + 0) * D_]; s1 += csH[(cc + 1) * D_];
            s2 += csH[(cc + 2) * D_]; s3 += csH[(cc + 3) * D_];
        }
        for (; cc < nH; ++cc) s0 += csH[cc * D_];
        for (int t = 0; t < nR; ++t) {
            if (t & 1) s1 += cs1[t * D_]; else s2 += cs1[t * D_];
        }
        float P0 = (s0 + s1) + (s2 + s3);
        float P1 = P0 + csum1[((size_t)bh * NC_ + c1) * D_ + lane];
        PF[lane]      = P0;
        PF[64 + lane] = P1;
    }
    __syncthreads();   // bar1: Pw (both halves) + PF visible

    // pB/zB prefetch (L2/L3-hot from launch A) — issued before PV MFMAs
    const float* pBr = pB + (size_t)bh * L_ * D_;
    const float* zBr = zB + (size_t)bh * L_;
    float pbv[16], zbv[16];
    #pragma unroll
    for (int r = 0; r < 16; ++r) {
        int m = (r & 3) + 8 * (r >> 2) + 4 * half;
        int i = T + m;
        pbv[r] = pBr[(size_t)i * D_ + d0 + ln];
        zbv[r] = zBr[i];
    }

    // PV over full 64-col band, this wave's 32 output dims (+ po on hf==1)
    f32x16 p = {}; f32x16 po = {};
    bf16x8 ones = ones_frag();
    #pragma unroll
    for (int kb = 0; kb < 4; ++kb) {
        int k0 = kb * 16 + half * 8;
        const float* pr = &Pw[ln * 68 + k0];
        float4 x = *(const float4*)pr;
        float4 y = *(const float4*)(pr + 4);
        bf16x8 ap;
        ap[0]=f2bf(x.x); ap[1]=f2bf(x.y); ap[2]=f2bf(x.z); ap[3]=f2bf(x.w);
        ap[4]=f2bf(y.x); ap[5]=f2bf(y.y); ap[6]=f2bf(y.z); ap[7]=f2bf(y.w);
        p = __builtin_amdgcn_mfma_f32_32x32x16_bf16(ap, bv[kb], p, 0, 0, 0);
        if (hf == 1)
            po = __builtin_amdgcn_mfma_f32_32x32x16_bf16(ap, ones, po, 0, 0, 0);
    }

    // hf==1 publishes the band denominator per row
    if (hf == 1) {
        #pragma unroll
        for (int r = 0; r < 16; ++r) {
            int m = (r & 3) + 8 * (r >> 2) + 4 * half;
            if (ln == 0) ZW[m] = po[r] - (float)((m & 15) + 1);
        }
    }
    __syncthreads();   // bar2: ZW visible

    // finalize: out = (band + strided + prefix) / z
    float Pf0 = PF[d0 + ln];
    float Pf1 = PF[64 + d0 + ln];
    #pragma unroll
    for (int r = 0; r < 16; ++r) {
        int m = (r & 3) + 8 * (r >> 2) + 4 * half;
        int i = T + m;
        float z   = ZW[m] + zbv[r] + (float)(i + 1);
        float num = p[r] + pbv[r] + (m < 16 ? Pf0 : Pf1);
        out[base + (size_t)i * RS_ + d0 + ln] = num / z;
    }
}

extern "C" void kernel_launch(void* const* d_in, const int* in_sizes, int n_in,
                              void* d_out, int out_size, void* d_ws, size_t ws_size,
                              hipStream_t stream) {
    const float* q = (const float*)d_in[0];
    const float* k = (const float*)d_in[1];
    const float* v = (const float*)d_in[2];
    // d_in[3] = attn_mask: deterministic causal — not read.
    float* out = (float*)d_out;

    float* csum1 = (float*)d_ws;                          // 131072 f
    float* pB    = csum1 + (size_t)B_ * H_ * NC_ * D_;    // 2097152 f
    float* zB    = pB    + (size_t)B_ * H_ * L_ * D_;     // 32768 f
    float* csumH = zB    + (size_t)B_ * H_ * L_;          // 16384 f

    // Launch A: 260 strided + 64 fused-csum blocks
    pre_k<<<324, 256, 0, stream>>>(q, k, v, csum1, csumH, pB, zB);
    // Launch B: 512 blocks (1024 local tiles), finalize fused
    local_k<<<512, 256, 0, stream>>>(q, k, v, csum1, csumH, pB, zB, out);
}